// Round 1
// baseline (7505.907 us; speedup 1.0000x reference)
//
#include <hip/hip_runtime.h>
#include <math.h>

// GPT-2 small fwd: B=2, S=1024, D=768, H=12, F=3072, L=4, V=50257. All fp32.
#define DD 768
#define NH 12
#define DH 64
#define FF 3072
#define NL 4
#define SS 1024
#define NB 2
#define TT (NB*SS)   // 2048 tokens
#define VV 50257

__device__ __forceinline__ float wred_sum(float v){
#pragma unroll
  for(int o=32;o>0;o>>=1) v += __shfl_xor(v,o);
  return v;
}
__device__ __forceinline__ float wred_max(float v){
#pragma unroll
  for(int o=32;o>0;o>>=1) v = fmaxf(v,__shfl_xor(v,o));
  return v;
}

// ---------------- embedding: x[t,:] = tok_emb[ids[t],:] + pos_emb[t%S,:] ----
__global__ __launch_bounds__(256) void embed_kernel(const int* __restrict__ ids,
    const float* __restrict__ tok, const float* __restrict__ pos,
    float* __restrict__ x){
  int t = blockIdx.x;
  int s = t & (SS-1);
  int id = ids[t];
  const float* te = tok + (size_t)id*DD;
  const float* pe = pos + (size_t)s*DD;
  float* xr = x + (size_t)t*DD;
#pragma unroll
  for(int i=0;i<3;i++){ int d = threadIdx.x + i*256; xr[d] = te[d] + pe[d]; }
}

// ---------------- LayerNorm (one block per token row, 768 = 3*256) ---------
__global__ __launch_bounds__(256) void ln_kernel(const float* __restrict__ in,
    const float* __restrict__ g, const float* __restrict__ b,
    float* __restrict__ out){
  __shared__ float red[4];
  int t = blockIdx.x; int tid = threadIdx.x;
  int lane = tid & 63, wid = tid >> 6;
  const float* xr = in + (size_t)t*DD;
  float v0 = xr[tid], v1 = xr[tid+256], v2 = xr[tid+512];
  float s = wred_sum(v0+v1+v2);
  if(lane==0) red[wid]=s;
  __syncthreads();
  float mu = (red[0]+red[1]+red[2]+red[3]) * (1.0f/DD);
  float d0=v0-mu, d1=v1-mu, d2=v2-mu;
  __syncthreads();
  float q = wred_sum(d0*d0+d1*d1+d2*d2);
  if(lane==0) red[wid]=q;
  __syncthreads();
  float var = (red[0]+red[1]+red[2]+red[3]) * (1.0f/DD);
  float rstd = rsqrtf(var + 1e-5f);
  float* orow = out + (size_t)t*DD;
  orow[tid]     = d0*rstd*g[tid]     + b[tid];
  orow[tid+256] = d1*rstd*g[tid+256] + b[tid+256];
  orow[tid+512] = d2*rstd*g[tid+512] + b[tid+512];
}

// ---------------- fp32 GEMM: C[M,N] = A[M,K] @ B + epilogue ----------------
// BT=false: B is [K,N] row-major (requires N%64==0 — true for all such calls).
// BT=true : B is [N,K] row-major (C = A @ B^T), N may be ragged (logits).
// Epilogue order: +bias -> GELU(exact erf) -> +resid. M must be %64==0.
template<bool BT, bool HASBIAS, bool RESID, bool GELU>
__global__ __launch_bounds__(256) void gemm_f32(
    const float* __restrict__ A, const float* __restrict__ Bm,
    const float* __restrict__ bias, const float* __restrict__ resid,
    float* __restrict__ C, int M, int N, int K){
  __shared__ float As[16][64];
  __shared__ float Bs[16][64];
  int tid = threadIdx.x;
  int tn = tid & 15, tm = tid >> 4;
  int row0 = blockIdx.y*64, col0 = blockIdx.x*64;
  float acc[4][4] = {};
  for(int k0=0;k0<K;k0+=16){
    {
      int r = tid >> 2, kq = (tid & 3)*4;
      float4 v = *reinterpret_cast<const float4*>(A + (size_t)(row0+r)*K + k0 + kq);
      As[kq+0][r]=v.x; As[kq+1][r]=v.y; As[kq+2][r]=v.z; As[kq+3][r]=v.w;
    }
    if(!BT){
      int kk = tid >> 4, nq = (tid & 15)*4;
      float4 v = *reinterpret_cast<const float4*>(Bm + (size_t)(k0+kk)*N + col0 + nq);
      Bs[kk][nq+0]=v.x; Bs[kk][nq+1]=v.y; Bs[kk][nq+2]=v.z; Bs[kk][nq+3]=v.w;
    } else {
      int n = tid >> 2, kq = (tid & 3)*4;
      int gn = col0 + n;
      float4 v = make_float4(0.f,0.f,0.f,0.f);
      if(gn < N) v = *reinterpret_cast<const float4*>(Bm + (size_t)gn*K + k0 + kq);
      Bs[kq+0][n]=v.x; Bs[kq+1][n]=v.y; Bs[kq+2][n]=v.z; Bs[kq+3][n]=v.w;
    }
    __syncthreads();
#pragma unroll
    for(int k=0;k<16;k++){
      float4 a  = *reinterpret_cast<const float4*>(&As[k][tm*4]);
      float4 bv = *reinterpret_cast<const float4*>(&Bs[k][tn*4]);
      float av[4] = {a.x,a.y,a.z,a.w};
      float bb[4] = {bv.x,bv.y,bv.z,bv.w};
#pragma unroll
      for(int i=0;i<4;i++)
#pragma unroll
        for(int j=0;j<4;j++) acc[i][j] += av[i]*bb[j];
    }
    __syncthreads();
  }
#pragma unroll
  for(int i=0;i<4;i++){
    int row = row0 + tm*4 + i;
#pragma unroll
    for(int j=0;j<4;j++){
      int col = col0 + tn*4 + j;
      if(col < N){
        float v = acc[i][j];
        if(HASBIAS) v += bias[col];
        if(GELU)    v = 0.5f*v*(1.0f + erff(v*0.70710678118654752f));
        if(RESID)   v += resid[(size_t)row*N+col];
        C[(size_t)row*N+col] = v;
      }
    }
  }
}

// ---------------- attention: one block per (q, h, b); causal softmax -------
// qkv layout: [T, 3*D]; q at col h*64+d, k at 768+h*64+d, v at 1536+h*64+d
__global__ __launch_bounds__(256) void attn_kernel(
    const float* __restrict__ qkv, float* __restrict__ out){
  int q = blockIdx.x, h = blockIdx.y, b = blockIdx.z;
  int tid = threadIdx.x;
  int lane = tid & 63, wid = tid >> 6;
  __shared__ float qv[64];
  __shared__ float sc[SS];
  __shared__ float red[4];
  __shared__ float pv[4][64];
  const size_t base = (size_t)b * SS * (3*DD);
  if(tid < 64) qv[tid] = qkv[base + (size_t)q*(3*DD) + h*64 + tid];
  __syncthreads();
  int nk = q + 1;
  float lmax = -INFINITY;
  for(int k = tid; k < nk; k += 256){
    const float* kr = qkv + base + (size_t)k*(3*DD) + DD + h*64;
    float s = 0.f;
#pragma unroll
    for(int d=0; d<64; d+=4){
      float4 kv4 = *reinterpret_cast<const float4*>(kr + d);
      s += qv[d]*kv4.x + qv[d+1]*kv4.y + qv[d+2]*kv4.z + qv[d+3]*kv4.w;
    }
    s *= 0.125f;   // 1/sqrt(64)
    sc[k] = s;
    lmax = fmaxf(lmax, s);
  }
  float wm = wred_max(lmax);
  if(lane==0) red[wid]=wm;
  __syncthreads();
  float m = fmaxf(fmaxf(red[0],red[1]), fmaxf(red[2],red[3]));
  float lsum = 0.f;
  for(int k = tid; k < nk; k += 256){
    float e = expf(sc[k] - m);
    sc[k] = e;
    lsum += e;
  }
  float wsum = wred_sum(lsum);
  __syncthreads();                 // red reads done; sc[] writes visible after
  if(lane==0) red[wid]=wsum;
  __syncthreads();
  float inv = 1.f/(red[0]+red[1]+red[2]+red[3]);
  // PV: thread = (group g in k, dh); partials reduced in LDS
  int dh = tid & 63, g = tid >> 6;
  float acc = 0.f;
  for(int k = g; k < nk; k += 4){
    acc += sc[k] * qkv[base + (size_t)k*(3*DD) + 2*DD + h*64 + dh];
  }
  pv[g][dh] = acc;
  __syncthreads();
  if(tid < 64){
    float r = (pv[0][tid]+pv[1][tid]+pv[2][tid]+pv[3][tid]) * inv;
    out[(size_t)(b*SS+q)*DD + h*64 + tid] = r;
  }
}

extern "C" void kernel_launch(void* const* d_in, const int* in_sizes, int n_in,
                              void* d_out, int out_size, void* d_ws, size_t ws_size,
                              hipStream_t stream) {
  const int*   ids   = (const int*)  d_in[0];
  const float* tok   = (const float*)d_in[1];
  const float* pos   = (const float*)d_in[2];
  const float* ln1_g = (const float*)d_in[3];
  const float* ln1_b = (const float*)d_in[4];
  const float* qkv_w = (const float*)d_in[5];
  const float* qkv_b = (const float*)d_in[6];
  const float* proj_w= (const float*)d_in[7];
  const float* proj_b= (const float*)d_in[8];
  const float* ln2_g = (const float*)d_in[9];
  const float* ln2_b = (const float*)d_in[10];
  const float* fc1_w = (const float*)d_in[11];
  const float* fc1_b = (const float*)d_in[12];
  const float* fc2_w = (const float*)d_in[13];
  const float* fc2_b = (const float*)d_in[14];
  const float* lnf_g = (const float*)d_in[15];
  const float* lnf_b = (const float*)d_in[16];
  float* out = (float*)d_out;

  float* ws   = (float*)d_ws;
  float* x    = ws;                              // [T,D]
  float* lnb  = x    + (size_t)TT*DD;            // [T,D]
  float* qkv  = lnb  + (size_t)TT*DD;            // [T,3D]
  float* attn = qkv  + (size_t)TT*3*DD;          // [T,D]
  float* ffh  = attn + (size_t)TT*DD;            // [T,F]

  embed_kernel<<<TT, 256, 0, stream>>>(ids, tok, pos, x);

  for(int l=0; l<NL; ++l){
    const float* l1g = ln1_g + (size_t)l*DD;
    const float* l1b = ln1_b + (size_t)l*DD;
    const float* qw  = qkv_w + (size_t)l*DD*(3*DD);
    const float* qb  = qkv_b + (size_t)l*(3*DD);
    const float* pw  = proj_w+ (size_t)l*DD*DD;
    const float* pb  = proj_b+ (size_t)l*DD;
    const float* l2g = ln2_g + (size_t)l*DD;
    const float* l2b = ln2_b + (size_t)l*DD;
    const float* f1w = fc1_w + (size_t)l*DD*FF;
    const float* f1b = fc1_b + (size_t)l*FF;
    const float* f2w = fc2_w + (size_t)l*FF*DD;
    const float* f2b = fc2_b + (size_t)l*DD;

    ln_kernel<<<TT, 256, 0, stream>>>(x, l1g, l1b, lnb);
    gemm_f32<false,true,false,false><<<dim3(3*DD/64, TT/64), 256, 0, stream>>>(
        lnb, qw, qb, nullptr, qkv, TT, 3*DD, DD);
    attn_kernel<<<dim3(SS, NH, NB), 256, 0, stream>>>(qkv, attn);
    gemm_f32<false,true,true,false><<<dim3(DD/64, TT/64), 256, 0, stream>>>(
        attn, pw, pb, x, x, TT, DD, DD);
    ln_kernel<<<TT, 256, 0, stream>>>(x, l2g, l2b, lnb);
    gemm_f32<false,true,false,true><<<dim3(FF/64, TT/64), 256, 0, stream>>>(
        lnb, f1w, f1b, nullptr, ffh, TT, FF, DD);
    gemm_f32<false,true,true,false><<<dim3(DD/64, TT/64), 256, 0, stream>>>(
        ffh, f2w, f2b, x, x, TT, DD, FF);
  }

  ln_kernel<<<TT, 256, 0, stream>>>(x, lnf_g, lnf_b, lnb);
  gemm_f32<true,false,false,false><<<dim3((VV+63)/64, TT/64), 256, 0, stream>>>(
      lnb, tok, nullptr, nullptr, out, TT, VV, DD);
}